// Round 7
// baseline (1089.033 us; speedup 1.0000x reference)
//
#include <hip/hip_runtime.h>
#include <hip/hip_fp16.h>

#define N_NODES 50000
#define N_EDGES 800000
#define FDIM 64
#define N_GRAPHS 500
#define OUTF 10
#define SENT N_NODES
#define ROWCAP 64                       // fixed CSR row capacity; Poisson(16), P(deg>64)~1e-18
#define EV4 (N_EDGES / 4)               // 200000 int4 edge quads
#define FB4 ((EV4 + 255) / 256)         // 782 virtual blocks per XCD group
#define SCANB (FB4 * 8)                 // 6256 scan virtual blocks (8 affinity groups)
#define GCNB ((N_NODES + 31) / 32)      // 1563 gcn virtual blocks (8 nodes/wave)
#define HEADB ((N_GRAPHS + 3) / 4)      // 125 head virtual blocks
#define GRID 768                        // 3 blocks/CU guaranteed by launch_bounds(256,3); co-resident by construction
#define NTHR (GRID * 256)

typedef _Float16 f16x8 __attribute__((ext_vector_type(8)));
typedef float f32x4 __attribute__((ext_vector_type(4)));

struct __align__(8)  H4 { __half2 a, b; };
struct __align__(16) H8 { __half2 a, b, c, d; };

__device__ __forceinline__ float rl(float v, int l) {
    return __int_as_float(__builtin_amdgcn_readlane(__float_as_int(v), l));
}

// ---------------- software grid barrier (plain launch; graph-capture-safe) ----------------
// Correct because all GRID blocks are co-resident (launch_bounds(256,3) caps VGPR
// so 3 blocks/CU are resource-guaranteed; 768 = 3*256). Per-phase slots: counter
// bar[p], flag bar[p+8] -> no reuse hazards within one execution. threadfence on
// BOTH sides replaces the driver's inter-dispatch cache maintenance (release-wb
// before arrival, acquire-inv after release). Bounded spin: a bug fails loud
// (wrong answer) instead of hanging the container.
__device__ __forceinline__ void gsync(int* bar, int p) {
    __threadfence();
    __syncthreads();
    if (threadIdx.x == 0) {
        int arrived = __hip_atomic_fetch_add(&bar[p], 1, __ATOMIC_ACQ_REL, __HIP_MEMORY_SCOPE_AGENT);
        if (arrived == GRID - 1) {
            __hip_atomic_store(&bar[p + 8], 1, __ATOMIC_RELEASE, __HIP_MEMORY_SCOPE_AGENT);
        } else {
            int spins = 0;
            while (__hip_atomic_load(&bar[p + 8], __ATOMIC_ACQUIRE, __HIP_MEMORY_SCOPE_AGENT) == 0) {
                __builtin_amdgcn_s_sleep(2);
                if (++spins > (1 << 24)) break;          // ~2s bound: never hang
            }
        }
    }
    __syncthreads();
    __threadfence();
}

// ---------------- fused GCN layer phase: 8 nodes/wave (16B gathers) + MFMA ----------------
// Identical math to R5's gcn_fused; vb replaces blockIdx.x. lgkmcnt(0) before the
// LDS write: a wave re-uses its private tile across vb iterations.
template <bool SCALE_OUT, bool POOL>
__device__ __forceinline__ void gcn_phase(
    int vb, int tid, __half (*A_lds)[8][72],
    const int* __restrict__ deg, const int* __restrict__ csr,
    const float* __restrict__ dinv, const __half* __restrict__ hs,
    const __half* __restrict__ Wh, const float* __restrict__ bias,
    __half* __restrict__ out, const int* __restrict__ batch,
    float* __restrict__ pooled) {
    int lane = tid & 63;
    int w = tid >> 6;
    int q8 = lane >> 3, L8 = lane & 7;                   // node 0..7, 16B chunk 0..7
    int nodeBase = (vb * 4 + w) * 8;
    int myN = nodeBase + q8;
    bool valid = myN < N_NODES;
    int myNc = valid ? myN : SENT;                       // sentinel row = zeros

    float dn = dinv[min(myN, N_NODES - 1)];
    int d = valid ? min(deg[min(myN, N_NODES - 1)], ROWCAP) : 0;
    int row = myNc << 6;
    int dpad = (d + 7) & ~7;

    H8 sv = *(const H8*)(hs + (size_t)myNc * FDIM + 8 * L8);   // self term
    __half2 z2 = __floats2half2_rn(0.f, 0.f);
    __half2 c0[4] = { sv.a, sv.b, sv.c, sv.d };          // chain 0 seeded with self
    __half2 c1[4] = { z2, z2, z2, z2 };

    int4 sA = *(const int4*)(csr + row);                 // prime index pipeline
    int4 sB = *(const int4*)(csr + row + 4);
    for (int base = 0; base < dpad; base += 8) {
        int nxt = min(base + 8, 56);                     // stays inside this node's row
        int4 nA = *(const int4*)(csr + row + nxt);
        int4 nB = *(const int4*)(csr + row + nxt + 4);
        int ss[8] = { sA.x, sA.y, sA.z, sA.w, sB.x, sB.y, sB.z, sB.w };
        #pragma unroll
        for (int j = 0; j < 8; ++j) {
            int e = base + j;
            int s = (e < d) ? ss[j] : SENT;              // mask pad garbage BEFORE load
            H8 hv = *(const H8*)(hs + (size_t)s * FDIM + 8 * L8);
            if (j & 1) {
                c1[0] = __hadd2(c1[0], hv.a); c1[1] = __hadd2(c1[1], hv.b);
                c1[2] = __hadd2(c1[2], hv.c); c1[3] = __hadd2(c1[3], hv.d);
            } else {
                c0[0] = __hadd2(c0[0], hv.a); c0[1] = __hadd2(c0[1], hv.b);
                c0[2] = __hadd2(c0[2], hv.c); c0[3] = __hadd2(c0[3], hv.d);
            }
        }
        sA = nA; sB = nB;
    }
    __half2 pk2[4];
    #pragma unroll
    for (int k = 0; k < 4; ++k) {
        float2 u = __half22float2(c0[k]);
        float2 v = __half22float2(c1[k]);
        pk2[k] = __floats2half2_rn((u.x + v.x) * dn, (u.y + v.y) * dn);
    }
    H8 pk = { pk2[0], pk2[1], pk2[2], pk2[3] };

    // ---- layout swap via wave-private LDS (no block barrier) ----
    asm volatile("s_waitcnt lgkmcnt(0)" ::: "memory");   // prior vb's reads done before overwrite
    *(H8*)&A_lds[w][q8][8 * L8] = pk;
    asm volatile("s_waitcnt lgkmcnt(0)" ::: "memory");
    __builtin_amdgcn_sched_barrier(0);
    int q = (lane >> 4) & 3, L = lane & 15;
    f16x8 a0 = *(const f16x8*)&A_lds[w][lane & 7][q * 8];
    f16x8 a1 = *(const f16x8*)&A_lds[w][lane & 7][32 + q * 8];

    // ---- 8x MFMA: 4 col-tiles, K=64 in two kk steps; C seeded with bias ----
    const f16x8* WB = (const f16x8*)Wh;       // [kk*4+g][c] f16x8, c = ct*16+L
    int cb = q * 64 + L;
    float b0 = bias[L], b1 = bias[16 + L], b2 = bias[32 + L], b3 = bias[48 + L];
    f32x4 C0 = {b0, b0, b0, b0}, C1 = {b1, b1, b1, b1};
    f32x4 C2 = {b2, b2, b2, b2}, C3 = {b3, b3, b3, b3};
    {
        f16x8 B0 = WB[cb], B1 = WB[cb + 16], B2 = WB[cb + 32], B3 = WB[cb + 48];
        C0 = __builtin_amdgcn_mfma_f32_16x16x32_f16(a0, B0, C0, 0, 0, 0);
        C1 = __builtin_amdgcn_mfma_f32_16x16x32_f16(a0, B1, C1, 0, 0, 0);
        C2 = __builtin_amdgcn_mfma_f32_16x16x32_f16(a0, B2, C2, 0, 0, 0);
        C3 = __builtin_amdgcn_mfma_f32_16x16x32_f16(a0, B3, C3, 0, 0, 0);
    }
    {
        f16x8 B0 = WB[cb + 256], B1 = WB[cb + 272], B2 = WB[cb + 288], B3 = WB[cb + 304];
        C0 = __builtin_amdgcn_mfma_f32_16x16x32_f16(a1, B0, C0, 0, 0, 0);
        C1 = __builtin_amdgcn_mfma_f32_16x16x32_f16(a1, B1, C1, 0, 0, 0);
        C2 = __builtin_amdgcn_mfma_f32_16x16x32_f16(a1, B2, C2, 0, 0, 0);
        C3 = __builtin_amdgcn_mfma_f32_16x16x32_f16(a1, B3, C3, 0, 0, 0);
    }

    // ---- epilogue: lane<32 holds rows 0-7 (node = nodeBase + (lane>>4)*4 + reg) ----
    int col = lane & 15;
    int half = (lane >> 4) & 1;
    if (POOL) {
        float p0 = fmaxf(C0[0],0.f)+fmaxf(C0[1],0.f)+fmaxf(C0[2],0.f)+fmaxf(C0[3],0.f);
        float p1 = fmaxf(C1[0],0.f)+fmaxf(C1[1],0.f)+fmaxf(C1[2],0.f)+fmaxf(C1[3],0.f);
        float p2 = fmaxf(C2[0],0.f)+fmaxf(C2[1],0.f)+fmaxf(C2[2],0.f)+fmaxf(C2[3],0.f);
        float p3 = fmaxf(C3[0],0.f)+fmaxf(C3[1],0.f)+fmaxf(C3[2],0.f)+fmaxf(C3[3],0.f);
        p0 += __shfl_down(p0, 16); p1 += __shfl_down(p1, 16);
        p2 += __shfl_down(p2, 16); p3 += __shfl_down(p3, 16);
        bool allv = (nodeBase + 7) < N_NODES;
        int g0 = batch[min(nodeBase,     N_NODES - 1)];
        int gL = batch[min(nodeBase + 7, N_NODES - 1)];
        if (allv && g0 == gL) {
            if (lane < 16) {
                atomicAdd(&pooled[g0 * FDIM +      col], p0);
                atomicAdd(&pooled[g0 * FDIM + 16 + col], p1);
                atomicAdd(&pooled[g0 * FDIM + 32 + col], p2);
                atomicAdd(&pooled[g0 * FDIM + 48 + col], p3);
            }
        } else if (lane < 32) {
            #pragma unroll
            for (int r = 0; r < 4; ++r) {
                int node = nodeBase + half * 4 + r;
                if (node < N_NODES) {
                    int g = batch[node];
                    atomicAdd(&pooled[g * FDIM +      col], fmaxf(C0[r], 0.f));
                    atomicAdd(&pooled[g * FDIM + 16 + col], fmaxf(C1[r], 0.f));
                    atomicAdd(&pooled[g * FDIM + 32 + col], fmaxf(C2[r], 0.f));
                    atomicAdd(&pooled[g * FDIM + 48 + col], fmaxf(C3[r], 0.f));
                }
            }
        }
    } else if (lane < 32) {
        #pragma unroll
        for (int r = 0; r < 4; ++r) {
            int nl = half * 4 + r;
            int node = nodeBase + nl;
            if (node < N_NODES) {
                float sc = 1.f;
                if (SCALE_OUT) sc = __shfl(dn, nl * 8);   // dn lives on lanes q8*8
                size_t ro = (size_t)node * FDIM;
                out[ro +      col] = __float2half_rn(fmaxf(C0[r], 0.f) * sc);
                out[ro + 16 + col] = __float2half_rn(fmaxf(C1[r], 0.f) * sc);
                out[ro + 32 + col] = __float2half_rn(fmaxf(C2[r], 0.f) * sc);
                out[ro + 48 + col] = __float2half_rn(fmaxf(C3[r], 0.f) * sc);
            }
        }
    }
}

// ---------------- ONE plain-launch persistent kernel, software grid sync ----------------
// R5 lesson: per-dispatch wins moved the total only 2-7us each -> the residual
// ~60us lives BETWEEN the 7 serialized dispatches. Fuse all phases; gsync between.
// R6 lesson: hipLaunchCooperativeKernel killed the container (graph-capture
// incompatibility suspected) -> plain launch + co-residency-guaranteed barrier.
__global__ __launch_bounds__(256, 3) void fused_all(
    const float* __restrict__ x, const int* __restrict__ src, const int* __restrict__ dst,
    const int* __restrict__ batch,
    const float* __restrict__ W1, const float* __restrict__ b1,
    const float* __restrict__ W2, const float* __restrict__ b2,
    const float* __restrict__ Wc, const float* __restrict__ bc,
    int* __restrict__ bar, int* __restrict__ deg, float* __restrict__ pooled,
    float* __restrict__ dinv, int* __restrict__ start, int* __restrict__ csr,
    __half* __restrict__ hsx, __half* __restrict__ hs1,
    __half* __restrict__ Wh1, __half* __restrict__ Wh2,
    float* __restrict__ out) {
    __shared__ __align__(16) __half A_lds[4][8][72];
    int tid = threadIdx.x;
    int gtid = blockIdx.x * 256 + tid;

    // ---- phase A: zero deg+pooled, sentinel rows, seg starts, W->f16 swizzle ----
    for (int i = gtid; i < N_NODES + N_GRAPHS * FDIM; i += NTHR) deg[i] = 0;  // pooled contiguous
    if (gtid < 2 * FDIM) {
        __half z = __float2half(0.f);
        if (gtid < FDIM) hsx[(size_t)N_NODES * FDIM + gtid] = z;
        else             hs1[(size_t)N_NODES * FDIM + gtid - FDIM] = z;
    }
    for (int i = gtid; i <= N_NODES; i += NTHR) {
        int b  = (i < N_NODES) ? batch[i] : N_GRAPHS;
        int bp = (i == 0) ? -1 : batch[i - 1];
        for (int g = bp + 1; g <= b; ++g) start[g] = i;
    }
    for (int oi = gtid; oi < 2 * FDIM * FDIM; oi += NTHR) {
        int wb = oi >> 12, o = oi & 4095;                // o = gk*512 + c*8 + j
        int j = o & 7, c = (o >> 3) & 63, gk = o >> 9;
        int k = (gk >> 2) * 32 + (gk & 3) * 8 + j;
        (wb ? Wh2 : Wh1)[o] = __float2half_rn((wb ? W2 : W1)[k * FDIM + c]);
    }
    gsync(bar, 0);

    // ---- phase B: edge scan, XCD-affinity ((d>>5)&7 == vb&7 == blockIdx&7) ----
    for (int vb = blockIdx.x; vb < SCANB; vb += GRID) {
        int myx = vb & 7;
        int t = (vb >> 3) * 256 + tid;
        if (t < EV4) {
            int4 d4 = ((const int4*)dst)[t];
            bool m0 = ((d4.x >> 5) & 7) == myx;
            bool m1 = ((d4.y >> 5) & 7) == myx;
            bool m2 = ((d4.z >> 5) & 7) == myx;
            bool m3 = ((d4.w >> 5) & 7) == myx;
            if (m0 | m1 | m2 | m3) {
                int4 s4 = ((const int4*)src)[t];
                if (m0) { int p = atomicAdd(&deg[d4.x], 1); if (p < ROWCAP) csr[d4.x * ROWCAP + p] = s4.x; }
                if (m1) { int p = atomicAdd(&deg[d4.y], 1); if (p < ROWCAP) csr[d4.y * ROWCAP + p] = s4.y; }
                if (m2) { int p = atomicAdd(&deg[d4.z], 1); if (p < ROWCAP) csr[d4.z * ROWCAP + p] = s4.z; }
                if (m3) { int p = atomicAdd(&deg[d4.w], 1); if (p < ROWCAP) csr[d4.w * ROWCAP + p] = s4.w; }
            }
        }
    }
    gsync(bar, 1);

    // ---- phase C: dinv + prescale x -> fp16 ----
    for (int gid = gtid; gid < N_NODES * 16; gid += NTHR) {
        int n = gid >> 4;
        float dn = rsqrtf((float)deg[n] + 1.0f);    // +1 self-loop
        if ((gid & 15) == 0) dinv[n] = dn;
        float4 vv = ((const float4*)x)[gid];
        H4 o;
        o.a = __floats2half2_rn(vv.x * dn, vv.y * dn);
        o.b = __floats2half2_rn(vv.z * dn, vv.w * dn);
        ((H4*)hsx)[gid] = o;
    }
    gsync(bar, 2);

    // ---- phase D: GCN layer 1 (scale rows by dinv for next gather) ----
    for (int vb = blockIdx.x; vb < GCNB; vb += GRID)
        gcn_phase<true, false>(vb, tid, A_lds, deg, csr, dinv, hsx, Wh1, b1,
                               hs1, nullptr, nullptr);
    gsync(bar, 3);

    // ---- phase E: GCN layer 2 + fused mean-pool atomics ----
    for (int vb = blockIdx.x; vb < GCNB; vb += GRID)
        gcn_phase<false, true>(vb, tid, A_lds, deg, csr, dinv, hs1, Wh2, b2,
                               nullptr, batch, pooled);
    gsync(bar, 4);

    // ---- phase F: head (mean + linear + log_softmax), one wave per graph ----
    for (int vb = blockIdx.x; vb < HEADB; vb += GRID) {
        int lane = tid & 63;
        int g = vb * 4 + (tid >> 6);
        int cnt = start[g + 1] - start[g];
        float c = (float)(cnt > 1 ? cnt : 1);
        float pm = pooled[g * FDIM + lane] / c;

        int j = (lane < OUTF) ? lane : 0;
        float a = bc[j];
        #pragma unroll
        for (int k = 0; k < 64; ++k) a = fmaf(rl(pm, k), Wc[k * OUTF + j], a);

        float m = -1e30f;
        #pragma unroll
        for (int i = 0; i < OUTF; ++i) m = fmaxf(m, rl(a, i));
        float s = 0.f;
        #pragma unroll
        for (int i = 0; i < OUTF; ++i) s += __expf(rl(a, i) - m);
        float lse = m + __logf(s);
        if (lane < OUTF) out[g * OUTF + lane] = a - lse;
    }
}

extern "C" void kernel_launch(void* const* d_in, const int* in_sizes, int n_in,
                              void* d_out, int out_size, void* d_ws, size_t ws_size,
                              hipStream_t stream) {
    const float* x     = (const float*)d_in[0];
    const int*   ei    = (const int*)d_in[1];
    const int*   batch = (const int*)d_in[2];
    const float* W1    = (const float*)d_in[3];
    const float* b1    = (const float*)d_in[4];
    const float* W2    = (const float*)d_in[5];
    const float* b2    = (const float*)d_in[6];
    const float* Wc    = (const float*)d_in[7];
    const float* bc    = (const float*)d_in[8];
    float* out = (float*)d_out;

    const int* src = ei;
    const int* dst = ei + N_EDGES;

    // workspace layout (int units); bar first (memset 64B/iter); csr 16B-aligned
    int*    ws     = (int*)d_ws;
    int*    bar    = ws;                                  // 16 (memset to 0)
    int*    deg    = bar + 16;                            // 50000 (zeroed in phase A)
    float*  pooled = (float*)(deg + N_NODES);             // 500*64 (zeroed in phase A)
    float*  dinv   = pooled + N_GRAPHS * FDIM;            // 50000
    int*    start  = (int*)(dinv + N_NODES);              // 504
    int*    csr    = start + N_GRAPHS + 4;                // 50000*64 = 3.2M ints (offset 132520: 16B-aligned)
    __half* hsx    = (__half*)(csr + N_NODES * ROWCAP);   // (N_NODES+1)*64 halves
    __half* hs1    = hsx + (size_t)(N_NODES + 1) * FDIM;
    __half* Wh1    = hs1 + (size_t)(N_NODES + 1) * FDIM;  // 4096 halves
    __half* Wh2    = Wh1 + FDIM * FDIM;                   // 4096 halves

    hipMemsetAsync(bar, 0, 16 * sizeof(int), stream);

    fused_all<<<GRID, 256, 0, stream>>>(x, src, dst, batch, W1, b1, W2, b2, Wc, bc,
                                        bar, deg, pooled, dinv, start, csr,
                                        hsx, hs1, Wh1, Wh2, out);
}

// Round 8
// 166.753 us; speedup vs baseline: 6.5308x; 6.5308x over previous
//
#include <hip/hip_runtime.h>
#include <hip/hip_fp16.h>

#define N_NODES 50000
#define N_EDGES 800000
#define FDIM 64
#define N_GRAPHS 500
#define OUTF 10
#define SENT N_NODES
#define ROWCAP 64                       // fixed CSR row capacity; Poisson(16), P(deg>64)~1e-18
#define EV4 (N_EDGES / 4)               // 200000 int4 edge quads
#define FB4 ((EV4 + 255) / 256)         // 782 blocks per XCD group
#define SCANB (FB4 * 8)                 // 6256 scan blocks (8 affinity groups)
#define CONVB (N_NODES * 16 / 256)      // 3125 x->fp16 convert blocks (exact)
#define SEGB ((N_NODES + 256) / 256)    // 196 seg-start blocks

typedef _Float16 f16x8 __attribute__((ext_vector_type(8)));
typedef float f32x4 __attribute__((ext_vector_type(4)));

struct __align__(8)  H4 { __half2 a, b; };
struct __align__(16) H8 { __half2 a, b, c, d; };

__device__ __forceinline__ float rl(float v, int l) {
    return __int_as_float(__builtin_amdgcn_readlane(__float_as_int(v), l));
}

// ---------------- CSR build (XCD-affinity scan) + x->fp16 conv + seg + W swizzle ----------------
// R7 lesson: the poison fill (44us, WRITE=256MB) is INSIDE the timed window; gaps
// between dispatches are only ~3us each -> multi-kernel structure is fine. The scan
// is atomic-round-trip bound (R3: VALU 0.4%, HBM 13%), so the x->fp16 conversion
// (pure BW) rides under it for free as independent blocks of the same dispatch.
// Affinity ((d>>5)&7 == bid&7) keeps csr/deg lines single-XCD-owned (R4 win).
__global__ __launch_bounds__(256) void fill_seg(
    const int* __restrict__ src, const int* __restrict__ dst,
    const float* __restrict__ x,
    int* __restrict__ deg, int* __restrict__ csr,
    const int* __restrict__ batch, int* __restrict__ start,
    const float* __restrict__ W1, const float* __restrict__ W2,
    __half* __restrict__ Wh1, __half* __restrict__ Wh2,
    __half* __restrict__ hsr) {
    int bid = blockIdx.x, tid = threadIdx.x;
    if (bid < SCANB) {
        int myx = bid & 7;                       // XCD proxy (dispatch round-robin)
        int t = (bid >> 3) * 256 + tid;
        if (t >= EV4) return;
        int4 d4 = ((const int4*)dst)[t];
        bool m0 = ((d4.x >> 5) & 7) == myx;
        bool m1 = ((d4.y >> 5) & 7) == myx;
        bool m2 = ((d4.z >> 5) & 7) == myx;
        bool m3 = ((d4.w >> 5) & 7) == myx;
        if (!(m0 | m1 | m2 | m3)) return;        // early-out before src load
        int4 s4 = ((const int4*)src)[t];
        if (m0) { int p = atomicAdd(&deg[d4.x], 1); if (p < ROWCAP) csr[d4.x * ROWCAP + p] = s4.x; }
        if (m1) { int p = atomicAdd(&deg[d4.y], 1); if (p < ROWCAP) csr[d4.y * ROWCAP + p] = s4.y; }
        if (m2) { int p = atomicAdd(&deg[d4.z], 1); if (p < ROWCAP) csr[d4.z * ROWCAP + p] = s4.z; }
        if (m3) { int p = atomicAdd(&deg[d4.w], 1); if (p < ROWCAP) csr[d4.w * ROWCAP + p] = s4.w; }
    } else if (bid < SCANB + CONVB) {
        int gid = (bid - SCANB) * 256 + tid;     // float4 index; CONVB*256 == N_NODES*16 exact
        float4 vv = ((const float4*)x)[gid];
        H4 o;
        o.a = __floats2half2_rn(vv.x, vv.y);     // unscaled; dinv applied in prescale pass
        o.b = __floats2half2_rn(vv.z, vv.w);
        ((H4*)hsr)[gid] = o;
    } else if (bid < SCANB + CONVB + SEGB) {
        int i = (bid - SCANB - CONVB) * 256 + tid;
        if (i > N_NODES) return;
        int b  = (i < N_NODES) ? batch[i] : N_GRAPHS;
        int bp = (i == 0) ? -1 : batch[i - 1];
        for (int g = bp + 1; g <= b; ++g) start[g] = i;
    } else {
        int wb = bid - (SCANB + CONVB + SEGB);   // 0: W1, 1: W2
        const float* Ws = wb ? W2 : W1;
        __half*      Wo = wb ? Wh2 : Wh1;
        int o0 = tid * 16;
        #pragma unroll
        for (int i = 0; i < 16; ++i) {
            int o = o0 + i;                      // o = gk*512 + c*8 + j
            int j = o & 7, c = (o >> 3) & 63, gk = o >> 9;
            int k = (gk >> 2) * 32 + (gk & 3) * 8 + j;
            Wo[o] = __float2half_rn(Ws[k * FDIM + c]);
        }
    }
}

// ---------------- dinv + scale raw fp16 features by dinv, + zero sentinel rows ----------------
// Light pass: 6.4MB read + 6.4MB write (was 12.8+6.4 reading fp32 x). fp32 math.
__global__ __launch_bounds__(256) void prescale(
    const int* __restrict__ deg, const __half* __restrict__ hsr,
    float* __restrict__ dinv, __half* __restrict__ hsx, __half* __restrict__ hs1) {
    if (blockIdx.x == 0 && threadIdx.x < 2 * FDIM) {
        __half z = __float2half(0.f);
        if (threadIdx.x < FDIM) hsx[(size_t)N_NODES * FDIM + threadIdx.x] = z;
        else                    hs1[(size_t)N_NODES * FDIM + threadIdx.x - FDIM] = z;
    }
    int i = blockIdx.x * 256 + threadIdx.x;      // H8 index: 8 per node
    if (i >= N_NODES * 8) return;
    int n = i >> 3;
    float dn = rsqrtf((float)deg[n] + 1.0f);     // +1 self-loop
    if ((i & 7) == 0) dinv[n] = dn;
    H8 v = ((const H8*)hsr)[i];
    float2 f0 = __half22float2(v.a), f1 = __half22float2(v.b);
    float2 f2 = __half22float2(v.c), f3 = __half22float2(v.d);
    H8 o;
    o.a = __floats2half2_rn(f0.x * dn, f0.y * dn);
    o.b = __floats2half2_rn(f1.x * dn, f1.y * dn);
    o.c = __floats2half2_rn(f2.x * dn, f2.y * dn);
    o.d = __floats2half2_rn(f3.x * dn, f3.y * dn);
    ((H8*)hsx)[i] = o;
}

// ---------------- fused GCN layer: 8 nodes/wave (16B gathers) + MFMA transform ----------------
// R5-proven kernel, verbatim. Gather is L2-line-request bound (800K x 2 x 64B
// lines/layer); 8 lanes/node x 16B, index double-buffer, dual fp16 chains.
// A-tile rows 0-7 = 8 real nodes (rows 8-15 duplicate; C rows 8-15 ignored).
// LDS stride 72 -> conflict-free both phases. Epilogue lanes 0-31
// (C: col=lane&15, row=(lane>>4)*4+reg). Pool fast path: shfl_down(.,16).
template <bool SCALE_OUT, bool POOL>
__global__ __launch_bounds__(256) void gcn_fused(
    const int* __restrict__ deg, const int* __restrict__ csr,
    const float* __restrict__ dinv, const __half* __restrict__ hs,
    const __half* __restrict__ Wh, const float* __restrict__ bias,
    __half* __restrict__ out, const int* __restrict__ batch,
    float* __restrict__ pooled) {
    __shared__ __align__(16) __half A_lds[4][8][72];
    int tid = threadIdx.x;
    int lane = tid & 63;
    int w = tid >> 6;
    int q8 = lane >> 3, L8 = lane & 7;                   // node 0..7, 16B chunk 0..7
    int nodeBase = (blockIdx.x * 4 + w) * 8;             // grid = 1563 (last block partial)
    int myN = nodeBase + q8;
    bool valid = myN < N_NODES;
    int myNc = valid ? myN : SENT;                       // sentinel row = zeros

    float dn = dinv[min(myN, N_NODES - 1)];
    int d = valid ? min(deg[min(myN, N_NODES - 1)], ROWCAP) : 0;
    int row = myNc << 6;
    int dpad = (d + 7) & ~7;

    H8 sv = *(const H8*)(hs + (size_t)myNc * FDIM + 8 * L8);   // self term
    __half2 z2 = __floats2half2_rn(0.f, 0.f);
    __half2 c0[4] = { sv.a, sv.b, sv.c, sv.d };          // chain 0 seeded with self
    __half2 c1[4] = { z2, z2, z2, z2 };

    int4 sA = *(const int4*)(csr + row);                 // prime index pipeline
    int4 sB = *(const int4*)(csr + row + 4);
    for (int base = 0; base < dpad; base += 8) {
        int nxt = min(base + 8, 56);                     // stays inside this node's row
        int4 nA = *(const int4*)(csr + row + nxt);
        int4 nB = *(const int4*)(csr + row + nxt + 4);
        int ss[8] = { sA.x, sA.y, sA.z, sA.w, sB.x, sB.y, sB.z, sB.w };
        #pragma unroll
        for (int j = 0; j < 8; ++j) {
            int e = base + j;
            int s = (e < d) ? ss[j] : SENT;              // mask pad garbage BEFORE load
            H8 hv = *(const H8*)(hs + (size_t)s * FDIM + 8 * L8);
            if (j & 1) {
                c1[0] = __hadd2(c1[0], hv.a); c1[1] = __hadd2(c1[1], hv.b);
                c1[2] = __hadd2(c1[2], hv.c); c1[3] = __hadd2(c1[3], hv.d);
            } else {
                c0[0] = __hadd2(c0[0], hv.a); c0[1] = __hadd2(c0[1], hv.b);
                c0[2] = __hadd2(c0[2], hv.c); c0[3] = __hadd2(c0[3], hv.d);
            }
        }
        sA = nA; sB = nB;
    }
    __half2 pk2[4];
    #pragma unroll
    for (int k = 0; k < 4; ++k) {
        float2 u = __half22float2(c0[k]);
        float2 v = __half22float2(c1[k]);
        pk2[k] = __floats2half2_rn((u.x + v.x) * dn, (u.y + v.y) * dn);
    }
    H8 pk = { pk2[0], pk2[1], pk2[2], pk2[3] };

    // ---- layout swap via wave-private LDS (no block barrier) ----
    *(H8*)&A_lds[w][q8][8 * L8] = pk;
    asm volatile("s_waitcnt lgkmcnt(0)" ::: "memory");
    __builtin_amdgcn_sched_barrier(0);
    int q = (lane >> 4) & 3, L = lane & 15;
    f16x8 a0 = *(const f16x8*)&A_lds[w][lane & 7][q * 8];
    f16x8 a1 = *(const f16x8*)&A_lds[w][lane & 7][32 + q * 8];

    // ---- 8x MFMA: 4 col-tiles, K=64 in two kk steps; C seeded with bias ----
    const f16x8* WB = (const f16x8*)Wh;       // [kk*4+g][c] f16x8, c = ct*16+L
    int cb = q * 64 + L;
    float b0 = bias[L], b1 = bias[16 + L], b2 = bias[32 + L], b3 = bias[48 + L];
    f32x4 C0 = {b0, b0, b0, b0}, C1 = {b1, b1, b1, b1};
    f32x4 C2 = {b2, b2, b2, b2}, C3 = {b3, b3, b3, b3};
    {
        f16x8 B0 = WB[cb], B1 = WB[cb + 16], B2 = WB[cb + 32], B3 = WB[cb + 48];
        C0 = __builtin_amdgcn_mfma_f32_16x16x32_f16(a0, B0, C0, 0, 0, 0);
        C1 = __builtin_amdgcn_mfma_f32_16x16x32_f16(a0, B1, C1, 0, 0, 0);
        C2 = __builtin_amdgcn_mfma_f32_16x16x32_f16(a0, B2, C2, 0, 0, 0);
        C3 = __builtin_amdgcn_mfma_f32_16x16x32_f16(a0, B3, C3, 0, 0, 0);
    }
    {
        f16x8 B0 = WB[cb + 256], B1 = WB[cb + 272], B2 = WB[cb + 288], B3 = WB[cb + 304];
        C0 = __builtin_amdgcn_mfma_f32_16x16x32_f16(a1, B0, C0, 0, 0, 0);
        C1 = __builtin_amdgcn_mfma_f32_16x16x32_f16(a1, B1, C1, 0, 0, 0);
        C2 = __builtin_amdgcn_mfma_f32_16x16x32_f16(a1, B2, C2, 0, 0, 0);
        C3 = __builtin_amdgcn_mfma_f32_16x16x32_f16(a1, B3, C3, 0, 0, 0);
    }

    // ---- epilogue: lane<32 holds rows 0-7 (node = nodeBase + (lane>>4)*4 + reg) ----
    int col = lane & 15;
    int half = (lane >> 4) & 1;
    if (POOL) {
        float p0 = fmaxf(C0[0],0.f)+fmaxf(C0[1],0.f)+fmaxf(C0[2],0.f)+fmaxf(C0[3],0.f);
        float p1 = fmaxf(C1[0],0.f)+fmaxf(C1[1],0.f)+fmaxf(C1[2],0.f)+fmaxf(C1[3],0.f);
        float p2 = fmaxf(C2[0],0.f)+fmaxf(C2[1],0.f)+fmaxf(C2[2],0.f)+fmaxf(C2[3],0.f);
        float p3 = fmaxf(C3[0],0.f)+fmaxf(C3[1],0.f)+fmaxf(C3[2],0.f)+fmaxf(C3[3],0.f);
        p0 += __shfl_down(p0, 16); p1 += __shfl_down(p1, 16);
        p2 += __shfl_down(p2, 16); p3 += __shfl_down(p3, 16);
        bool allv = (nodeBase + 7) < N_NODES;
        int g0 = batch[min(nodeBase,     N_NODES - 1)];
        int gL = batch[min(nodeBase + 7, N_NODES - 1)];
        if (allv && g0 == gL) {
            if (lane < 16) {
                atomicAdd(&pooled[g0 * FDIM +      col], p0);
                atomicAdd(&pooled[g0 * FDIM + 16 + col], p1);
                atomicAdd(&pooled[g0 * FDIM + 32 + col], p2);
                atomicAdd(&pooled[g0 * FDIM + 48 + col], p3);
            }
        } else if (lane < 32) {
            #pragma unroll
            for (int r = 0; r < 4; ++r) {
                int node = nodeBase + half * 4 + r;
                if (node < N_NODES) {
                    int g = batch[node];
                    atomicAdd(&pooled[g * FDIM +      col], fmaxf(C0[r], 0.f));
                    atomicAdd(&pooled[g * FDIM + 16 + col], fmaxf(C1[r], 0.f));
                    atomicAdd(&pooled[g * FDIM + 32 + col], fmaxf(C2[r], 0.f));
                    atomicAdd(&pooled[g * FDIM + 48 + col], fmaxf(C3[r], 0.f));
                }
            }
        }
    } else if (lane < 32) {
        #pragma unroll
        for (int r = 0; r < 4; ++r) {
            int nl = half * 4 + r;
            int node = nodeBase + nl;
            if (node < N_NODES) {
                float sc = 1.f;
                if (SCALE_OUT) sc = __shfl(dn, nl * 8);   // dn lives on lanes q8*8
                size_t ro = (size_t)node * FDIM;
                out[ro +      col] = __float2half_rn(fmaxf(C0[r], 0.f) * sc);
                out[ro + 16 + col] = __float2half_rn(fmaxf(C1[r], 0.f) * sc);
                out[ro + 32 + col] = __float2half_rn(fmaxf(C2[r], 0.f) * sc);
                out[ro + 48 + col] = __float2half_rn(fmaxf(C3[r], 0.f) * sc);
            }
        }
    }
}

// ---------------- tiny head: mean + linear + log_softmax from pooled sums ----------------
__global__ __launch_bounds__(256) void head(
    const float* __restrict__ pooled, const int* __restrict__ start,
    const float* __restrict__ Wc, const float* __restrict__ bc,
    float* __restrict__ out) {
    int tid = threadIdx.x;
    int lane = tid & 63;
    int g = blockIdx.x * 4 + (tid >> 6);
    int cnt = start[g + 1] - start[g];
    float c = (float)(cnt > 1 ? cnt : 1);
    float pm = pooled[g * FDIM + lane] / c;

    int j = (lane < OUTF) ? lane : 0;
    float a = bc[j];
    #pragma unroll
    for (int k = 0; k < 64; ++k) a = fmaf(rl(pm, k), Wc[k * OUTF + j], a);

    float m = -1e30f;
    #pragma unroll
    for (int i = 0; i < OUTF; ++i) m = fmaxf(m, rl(a, i));
    float s = 0.f;
    #pragma unroll
    for (int i = 0; i < OUTF; ++i) s += __expf(rl(a, i) - m);
    float lse = m + __logf(s);
    if (lane < OUTF) out[g * OUTF + lane] = a - lse;
}

extern "C" void kernel_launch(void* const* d_in, const int* in_sizes, int n_in,
                              void* d_out, int out_size, void* d_ws, size_t ws_size,
                              hipStream_t stream) {
    const float* x     = (const float*)d_in[0];
    const int*   ei    = (const int*)d_in[1];
    const int*   batch = (const int*)d_in[2];
    const float* W1    = (const float*)d_in[3];
    const float* b1    = (const float*)d_in[4];
    const float* W2    = (const float*)d_in[5];
    const float* b2    = (const float*)d_in[6];
    const float* Wc    = (const float*)d_in[7];
    const float* bc    = (const float*)d_in[8];
    float* out = (float*)d_out;

    const int* src = ei;
    const int* dst = ei + N_EDGES;

    // workspace layout (int units); csr base 16B-aligned; hsr (raw fp16 x) after Wh2
    int*    ws     = (int*)d_ws;
    int*    deg    = ws;                                  // 50000 (memset to 0)
    float*  pooled = (float*)(deg + N_NODES);             // 500*64 (memset to 0)
    float*  dinv   = pooled + N_GRAPHS * FDIM;            // 50000
    int*    start  = (int*)(dinv + N_NODES);              // 504
    int*    csr    = start + N_GRAPHS + 4;                // 50000*64 = 3.2M ints
    __half* hsx    = (__half*)(csr + N_NODES * ROWCAP);   // (N_NODES+1)*64 halves
    __half* hs1    = hsx + (size_t)(N_NODES + 1) * FDIM;
    __half* Wh1    = hs1 + (size_t)(N_NODES + 1) * FDIM;  // 4096 halves
    __half* Wh2    = Wh1 + FDIM * FDIM;                   // 4096 halves
    __half* hsr    = Wh2 + FDIM * FDIM;                   // 50000*64 halves (raw fp16 x)

    hipMemsetAsync(deg, 0, (N_NODES + N_GRAPHS * FDIM) * sizeof(int), stream);

    fill_seg <<<SCANB + CONVB + SEGB + 2, 256, 0, stream>>>(
        src, dst, x, deg, csr, batch, start, W1, W2, Wh1, Wh2, hsr);
    prescale <<<(N_NODES * 8 + 255) / 256, 256, 0, stream>>>(deg, hsr, dinv, hsx, hs1);

    const int gcnGrid = (N_NODES + 31) / 32;  // 1563, 8 nodes/wave
    gcn_fused<true , false><<<gcnGrid, 256, 0, stream>>>(deg, csr, dinv, hsx, Wh1, b1, hs1, nullptr, nullptr);
    gcn_fused<false, true ><<<gcnGrid, 256, 0, stream>>>(deg, csr, dinv, hs1, Wh2, b2, nullptr, batch, pooled);

    head<<<N_GRAPHS / 4, 256, 0, stream>>>(pooled, start, Wc, bc, out);
}